// Round 14
// baseline (1154.418 us; speedup 1.0000x reference)
//
#include <hip/hip_runtime.h>
#include <stdint.h>

// x[N,128] f32, edge_index[2,E] int32/64, ew[E] f32, W1[64,128], b1[64], W2[128,64], b2[128]
#define FIN 128
#define FHID 64
#define CHUNK 2048
#define FIX_SCALE 65536.0f      // 2^16 fixed point for weighted degree
#define FIX_INV   (1.0f / 65536.0f)
#define AGG_SC    262144.0f     // 2^18 fixed point for order-invariant aggregation
#define AGG_INV   (1.0f / 262144.0f)

__device__ __forceinline__ float bf2f(unsigned short u) {
    union { unsigned int i; float f; } v; v.i = ((unsigned int)u) << 16; return v.f;
}
__device__ __forceinline__ unsigned short f2bf(float f) {
    union { float f; unsigned int i; } v; v.f = f;
    unsigned int u = v.i;
    u += 0x7FFFu + ((u >> 16) & 1u);   // round-to-nearest-even
    return (unsigned short)(u >> 16);
}

// ---------- dtype detection: int64 edge_index has odd 32-bit words == 0 ----------
__global__ void k_detect(const uint32_t* __restrict__ ei, int* __restrict__ flag) {
    if (blockIdx.x == 0 && threadIdx.x == 0) {
        uint32_t o = 0;
        #pragma unroll
        for (int i = 1; i < 16; i += 2) o |= ei[i];
        *flag = (o == 0) ? 1 : 0;
    }
}

__device__ __forceinline__ int edge_at(const void* ei, long long idx, int is64) {
    if (is64) return (int)((const long long*)ei)[idx];
    return ((const int*)ei)[idx];
}

// ---------- FUSED: gemm1 tile (every 4th block) + packed-degree histogram ----------
// r13 lesson: gemm blocks must be SPREAD over dispatch order (not front-loaded)
// and LDS must stay small so atomic-only blocks keep occupancy. Wt is staged in
// four 32-k phases (8.3 KB) + xt 16 KB = 24.4 KB -> 6 blocks/CU.
__global__ __launch_bounds__(256) void k_deg_gemm1(const float* __restrict__ x, const float* __restrict__ W1,
                                                   unsigned short* __restrict__ h1lin,
                                                   const void* __restrict__ ei, const float* __restrict__ w,
                                                   unsigned int* __restrict__ packed,
                                                   unsigned char* __restrict__ rank,
                                                   const int* __restrict__ flag, int E, int N, int g1b) {
    __shared__ float Wt[32 * 65];       // 8.3 KB, one k-phase of W1 transposed
    __shared__ float xt[32 * FIN];      // 16 KB
    int gblk = blockIdx.x >> 2;
    if ((blockIdx.x & 3) == 0 && gblk < g1b) {
        int t = threadIdx.x;
        int r0 = gblk * 32;
        const float4* xg = (const float4*)(x + (size_t)r0 * FIN);
        float4* xt4 = (float4*)xt;
        #pragma unroll
        for (int q = 0; q < 4; ++q) {
            int i = t + q * 256;
            if (r0 + (i >> 5) < N) xt4[i] = xg[i];
        }
        int j = t & 63, rg = t >> 6;
        float acc[8];
        #pragma unroll
        for (int r = 0; r < 8; ++r) acc[r] = 0.f;
        for (int ph = 0; ph < 4; ++ph) {
            __syncthreads();            // prior-phase reads done (and xt staged, ph=0)
            for (int i = t; i < 64 * 32; i += 256) {
                int jj = i >> 5, kk = i & 31;
                Wt[kk * 65 + jj] = W1[jj * FIN + ph * 32 + kk];   // coalesced read
            }
            __syncthreads();
            #pragma unroll
            for (int kk = 0; kk < 32; kk += 4) {
                float w0 = Wt[(kk + 0) * 65 + j];
                float w1 = Wt[(kk + 1) * 65 + j];
                float w2 = Wt[(kk + 2) * 65 + j];
                float w3 = Wt[(kk + 3) * 65 + j];
                #pragma unroll
                for (int r = 0; r < 8; ++r) {
                    float4 xv = xt4[(rg * 8 + r) * 32 + ((ph * 32 + kk) >> 2)];
                    acc[r] += xv.x * w0 + xv.y * w1 + xv.z * w2 + xv.w * w3;
                }
            }
        }
        #pragma unroll
        for (int r = 0; r < 8; ++r) {
            int row = r0 + rg * 8 + r;
            if (row < N) h1lin[(size_t)row * FHID + j] = f2bf(acc[r]);
        }
    }
    // ---- edge histogram part (all blocks) ----
    int e = blockIdx.x * 256 + threadIdx.x;
    if (e >= E) return;
    int is64 = *flag;
    int c = edge_at(ei, (long long)E + e, is64);
    unsigned int inc = (1u << 24) | __float2uint_rn(w[e] * FIX_SCALE);
    unsigned int old = atomicAdd(&packed[c], inc);
    rank[e] = (unsigned char)(old >> 24);
}

// ---------- packed -> deg^-1/2 ----------
__global__ __launch_bounds__(256) void k_dis(const unsigned int* __restrict__ packed,
                                             float* __restrict__ dis, int N) {
    int i = blockIdx.x * 256 + threadIdx.x;
    if (i < N) {
        float d = (float)(packed[i] & 0xFFFFFFu) * FIX_INV;
        dis[i] = (d > 0.f) ? rsqrtf(d) : 0.f;
    }
}

// ---------- t1 = dis[row] * h1lin (in place, deterministic) ----------
__global__ __launch_bounds__(256) void k_scale(unsigned int* __restrict__ t,
                                               const float* __restrict__ dis, int total) {
    int i = blockIdx.x * 256 + threadIdx.x;
    if (i >= total) return;
    float d = dis[i >> 5];                  // 32 consecutive words share one node
    unsigned v = t[i];
    t[i] = (unsigned)f2bf(bf2f((unsigned short)v) * d)
         | ((unsigned)f2bf(bf2f((unsigned short)(v >> 16)) * d) << 16);
}

// ---------- exclusive scan of packed counts -> row_start ----------
__global__ __launch_bounds__(256) void k_scan_part(const unsigned int* __restrict__ packed,
                                                   int* __restrict__ partial, int N) {
    __shared__ int sdata[256];
    int b = blockIdx.x, t = threadIdx.x;
    int base = b * CHUNK;
    int sum = 0;
    #pragma unroll
    for (int q = 0; q < CHUNK / 256; ++q) {
        int idx = base + q * 256 + t;
        if (idx < N) sum += (int)(packed[idx] >> 24);
    }
    sdata[t] = sum; __syncthreads();
    for (int off = 128; off > 0; off >>= 1) {
        if (t < off) sdata[t] += sdata[t + off];
        __syncthreads();
    }
    if (t == 0) partial[b] = sdata[0];
}

__global__ void k_scan_top(int* partial, int nparts, int* row_start, int N) {
    if (blockIdx.x == 0 && threadIdx.x == 0) {
        int run = 0;
        for (int i = 0; i < nparts; ++i) { int v = partial[i]; partial[i] = run; run += v; }
        row_start[N] = run;   // == E
    }
}

__global__ __launch_bounds__(256) void k_scan_chunk(const unsigned int* __restrict__ packed,
                                                    const int* __restrict__ partial,
                                                    int* __restrict__ row_start, int N) {
    __shared__ int tsum[256];
    __shared__ int toff[256];
    int b = blockIdx.x, t = threadIdx.x;
    int base = b * CHUNK + t * 8;
    int v[8]; int s = 0;
    #pragma unroll
    for (int q = 0; q < 8; ++q) {
        int idx = base + q;
        v[q] = (idx < N) ? (int)(packed[idx] >> 24) : 0;
        s += v[q];
    }
    tsum[t] = s; __syncthreads();
    if (t == 0) {
        int run = partial[b];
        for (int i = 0; i < 256; ++i) { int x = tsum[i]; toff[i] = run; run += x; }
    }
    __syncthreads();
    int ex = toff[t];
    #pragma unroll
    for (int q = 0; q < 8; ++q) {
        int idx = base + q;
        if (idx < N) row_start[idx] = ex;
        ex += v[q];
    }
}

// ---------- CSR fill (atomic-free, no dis gathers): csr = {src, w} ----------
__global__ __launch_bounds__(256) void k_fill(const void* __restrict__ ei, const float* __restrict__ w,
                                              const int* __restrict__ row_start,
                                              const unsigned char* __restrict__ rank,
                                              int2* __restrict__ csr,
                                              const int* __restrict__ flag, int E) {
    int e = blockIdx.x * 256 + threadIdx.x;
    if (e >= E) return;
    int is64 = *flag;
    int r = edge_at(ei, e, is64);
    int c = edge_at(ei, (long long)E + e, is64);
    int pos = row_start[c] + (int)rank[e];
    csr[pos] = make_int2(r, __float_as_int(w[e]));
}

// ---------- dual-node interleaved pair-gather aggregation (int-fx, order-invariant) ----------
// acc = sum w * tab[src]; caller multiplies by dis[node] (factored-out dis[c]).
// OUT_MODE 0 (agg1): t2 = dis*relu(dis*acc + b1);  OUT_MODE 1 (agg2): aggv = dis*acc
template <int OUT_MODE>
__device__ __forceinline__ void agg_fx_dual(const int2* __restrict__ csr, const int* __restrict__ row_start,
                                            const unsigned int* __restrict__ tab32,
                                            const float* __restrict__ b1, const float* __restrict__ dis,
                                            unsigned int* __restrict__ out32, int N) {
    int wid = threadIdx.x >> 6, lane = threadIdx.x & 63;
    int nodeA = blockIdx.x * 8 + wid * 2;
    if (nodeA >= N) return;
    int nodeB = nodeA + 1;
    bool hasB = nodeB < N;
    int half = lane >> 5, lpos = lane & 31;
    int baseA = row_start[nodeA], eA = row_start[nodeA + 1];
    int baseB = hasB ? eA : 0, eB = hasB ? row_start[nodeB + 1] : 0;
    int aAx0 = 0, aAy0 = 0, aAx1 = 0, aAy1 = 0;
    int aBx0 = 0, aBy0 = 0, aBx1 = 0, aBy1 = 0;
    while (baseA < eA || baseB < eB) {
        int mA = eA - baseA; mA = mA < 0 ? 0 : (mA > 64 ? 64 : mA);
        int mB = eB - baseB; mB = mB < 0 ? 0 : (mB > 64 ? 64 : mB);
        int2 entA = (lane < mA) ? csr[baseA + lane] : make_int2(0, 0);
        int2 entB = (lane < mB) ? csr[baseB + lane] : make_int2(0, 0);
        int mMax = mA > mB ? mA : mB;
        int i = 0;
        for (; i + 4 <= mMax; i += 4) {
            if (i < mA) {
                int s0 = __shfl(entA.x, i + half);     float n0 = __shfl(__int_as_float(entA.y), i + half);
                int s1 = __shfl(entA.x, i + 2 + half); float n1 = __shfl(__int_as_float(entA.y), i + 2 + half);
                unsigned v0 = tab32[(size_t)((unsigned)s0 << 5) + lpos];
                unsigned v1 = tab32[(size_t)((unsigned)s1 << 5) + lpos];
                float f0 = n0 * AGG_SC, f1 = n1 * AGG_SC;
                aAx0 += __float2int_rz(f0 * bf2f((unsigned short)v0));
                aAy0 += __float2int_rz(f0 * bf2f((unsigned short)(v0 >> 16)));
                aAx1 += __float2int_rz(f1 * bf2f((unsigned short)v1));
                aAy1 += __float2int_rz(f1 * bf2f((unsigned short)(v1 >> 16)));
            }
            if (i < mB) {
                int s0 = __shfl(entB.x, i + half);     float n0 = __shfl(__int_as_float(entB.y), i + half);
                int s1 = __shfl(entB.x, i + 2 + half); float n1 = __shfl(__int_as_float(entB.y), i + 2 + half);
                unsigned v0 = tab32[(size_t)((unsigned)s0 << 5) + lpos];
                unsigned v1 = tab32[(size_t)((unsigned)s1 << 5) + lpos];
                float f0 = n0 * AGG_SC, f1 = n1 * AGG_SC;
                aBx0 += __float2int_rz(f0 * bf2f((unsigned short)v0));
                aBy0 += __float2int_rz(f0 * bf2f((unsigned short)(v0 >> 16)));
                aBx1 += __float2int_rz(f1 * bf2f((unsigned short)v1));
                aBy1 += __float2int_rz(f1 * bf2f((unsigned short)(v1 >> 16)));
            }
        }
        for (; i < mMax; ++i) {
            if (i < mA) {
                int s0 = __shfl(entA.x, i); float n0 = __shfl(__int_as_float(entA.y), i);
                if (half) n0 = 0.f;
                unsigned v0 = tab32[(size_t)((unsigned)s0 << 5) + lpos];
                float f0 = n0 * AGG_SC;
                aAx0 += __float2int_rz(f0 * bf2f((unsigned short)v0));
                aAy0 += __float2int_rz(f0 * bf2f((unsigned short)(v0 >> 16)));
            }
            if (i < mB) {
                int s0 = __shfl(entB.x, i); float n0 = __shfl(__int_as_float(entB.y), i);
                if (half) n0 = 0.f;
                unsigned v0 = tab32[(size_t)((unsigned)s0 << 5) + lpos];
                float f0 = n0 * AGG_SC;
                aBx0 += __float2int_rz(f0 * bf2f((unsigned short)v0));
                aBy0 += __float2int_rz(f0 * bf2f((unsigned short)(v0 >> 16)));
            }
        }
        baseA += 64; baseB += 64;
    }
    int axA = aAx0 + aAx1, ayA = aAy0 + aAy1;
    axA += __shfl_xor(axA, 32); ayA += __shfl_xor(ayA, 32);   // int: order-invariant
    int axB = aBx0 + aBx1, ayB = aBy0 + aBy1;
    axB += __shfl_xor(axB, 32); ayB += __shfl_xor(ayB, 32);
    if (lane < 32) {
        float dA = dis[nodeA];
        float dB = hasB ? dis[nodeB] : 0.f;
        float fxA = (float)axA * AGG_INV * dA, fyA = (float)ayA * AGG_INV * dA;
        float fxB = (float)axB * AGG_INV * dB, fyB = (float)ayB * AGG_INV * dB;
        if (OUT_MODE == 0) {
            float2 bp = ((const float2*)b1)[lane];
            fxA = dA * fmaxf(fxA + bp.x, 0.f); fyA = dA * fmaxf(fyA + bp.y, 0.f);
            fxB = dB * fmaxf(fxB + bp.x, 0.f); fyB = dB * fmaxf(fyB + bp.y, 0.f);
        }
        out32[(size_t)nodeA * 32 + lane] = (unsigned)f2bf(fxA) | ((unsigned)f2bf(fyA) << 16);
        if (hasB)
            out32[(size_t)nodeB * 32 + lane] = (unsigned)f2bf(fxB) | ((unsigned)f2bf(fyB) << 16);
    }
}

__global__ __launch_bounds__(256) void k_agg1(const int2* __restrict__ csr, const int* __restrict__ row_start,
                                              const unsigned int* __restrict__ t1,
                                              const float* __restrict__ b1, const float* __restrict__ dis,
                                              unsigned int* __restrict__ t2, int N) {
    agg_fx_dual<0>(csr, row_start, t1, b1, dis, t2, N);
}

__global__ __launch_bounds__(256) void k_agg2(const int2* __restrict__ csr, const int* __restrict__ row_start,
                                              const unsigned int* __restrict__ t2,
                                              const float* __restrict__ dis,
                                              unsigned int* __restrict__ aggv32, int N) {
    agg_fx_dual<1>(csr, row_start, t2, (const float*)nullptr, dis, aggv32, N);
}

// ---------- GEMM2: out[N,128] = relu(aggv[N,64](bf16) @ W2[128,64]^T + b2) ----------
#define G2_ROWS 16
__global__ __launch_bounds__(256, 4) void k_gemm2(const unsigned int* __restrict__ aggv32,
                                                  const float* __restrict__ W2,
                                                  const float* __restrict__ b2,
                                                  float* __restrict__ out, int N) {
    __shared__ float Wt[FHID * 129];            // Wt[k*129+j] = W2[j*64+k]; conflict-free
    __shared__ unsigned int at[G2_ROWS * 33];
    int t = threadIdx.x;
    for (int i = t; i < FIN * FHID; i += 256) {
        int j = i >> 6, k = i & 63;
        Wt[k * 129 + j] = W2[i];
    }
    int r0 = blockIdx.x * G2_ROWS;
    for (int i = t; i < G2_ROWS * 32; i += 256) {
        int r = i >> 5, c = i & 31;
        at[r * 33 + c] = (r0 + r < N) ? aggv32[(size_t)(r0 + r) * 32 + c] : 0u;
    }
    __syncthreads();
    int j = t & 127, rg = t >> 7;
    float acc[8];
    #pragma unroll
    for (int r = 0; r < 8; ++r) acc[r] = 0.f;
    for (int c = 0; c < 32; c += 2) {
        float w0 = Wt[(2 * c + 0) * 129 + j];
        float w1 = Wt[(2 * c + 1) * 129 + j];
        float w2 = Wt[(2 * c + 2) * 129 + j];
        float w3 = Wt[(2 * c + 3) * 129 + j];
        #pragma unroll
        for (int r = 0; r < 8; ++r) {
            unsigned a01 = at[(rg * 8 + r) * 33 + c];
            unsigned a23 = at[(rg * 8 + r) * 33 + c + 1];
            acc[r] += bf2f((unsigned short)a01) * w0 + bf2f((unsigned short)(a01 >> 16)) * w1
                    + bf2f((unsigned short)a23) * w2 + bf2f((unsigned short)(a23 >> 16)) * w3;
        }
    }
    float bj = b2[j];
    #pragma unroll
    for (int r = 0; r < 8; ++r) {
        int row = r0 + rg * 8 + r;
        if (row < N) out[(size_t)row * FIN + j] = fmaxf(acc[r] + bj, 0.f);
    }
}

extern "C" void kernel_launch(void* const* d_in, const int* in_sizes, int n_in,
                              void* d_out, int out_size, void* d_ws, size_t ws_size,
                              hipStream_t stream) {
    const float* x  = (const float*)d_in[0];
    const void*  ei = d_in[1];
    const float* w  = (const float*)d_in[2];
    const float* W1 = (const float*)d_in[3];
    const float* b1 = (const float*)d_in[4];
    const float* W2 = (const float*)d_in[5];
    const float* b2 = (const float*)d_in[6];
    float* out = (float*)d_out;
    int N = in_sizes[0] / FIN;
    int E = in_sizes[2];

    char* ws = (char*)d_ws;
    size_t off = 0;
    auto alloc = [&](size_t b) { size_t o = off; off = (off + b + 255) & ~255ULL; return o; };
    int*   flag      = (int*)(ws + alloc(4));
    unsigned int* packed = (unsigned int*)(ws + alloc((size_t)N * 4));
    float* dis       = (float*)(ws + alloc((size_t)N * 4));
    int*   row_start = (int*)(ws + alloc((size_t)(N + 1) * 4));
    int*   partial   = (int*)(ws + alloc(4096));
    int2*  csr       = (int2*)(ws + alloc((size_t)E * 8));
    unsigned char* rank = (unsigned char*)(ws + alloc((size_t)E));   // own slot (fused kernel writes h1lin too)
    unsigned int* t2_32   = (unsigned int*)(ws + alloc((size_t)N * FHID * 2));
    unsigned int* aggv32  = (unsigned int*)(ws + alloc((size_t)N * FHID * 2));
    unsigned int* t1_32   = (unsigned int*)(ws + alloc((size_t)N * FHID * 2));  // h1lin then t1 (scaled in place)

    hipMemsetAsync(packed, 0, (size_t)N * 4, stream);

    k_detect<<<1, 64, 0, stream>>>((const uint32_t*)ei, flag);

    int eb = (E + 255) / 256;
    int g1b = (N + 31) / 32;
    int fused_grid = eb > 4 * g1b ? eb : 4 * g1b;
    k_deg_gemm1<<<fused_grid, 256, 0, stream>>>(x, W1, (unsigned short*)t1_32, ei, w,
                                                packed, rank, flag, E, N, g1b);
    k_dis<<<(N + 255) / 256, 256, 0, stream>>>(packed, dis, N);
    k_scale<<<(N * 32 + 255) / 256, 256, 0, stream>>>(t1_32, dis, N * 32);

    int nparts = (N + CHUNK - 1) / CHUNK;
    k_scan_part<<<nparts, 256, 0, stream>>>(packed, partial, N);
    k_scan_top<<<1, 64, 0, stream>>>(partial, nparts, row_start, N);
    k_scan_chunk<<<nparts, 256, 0, stream>>>(packed, partial, row_start, N);

    k_fill<<<eb, 256, 0, stream>>>(ei, w, row_start, rank, csr, flag, E);

    k_agg1<<<(N + 7) / 8, 256, 0, stream>>>(csr, row_start, t1_32, b1, dis, t2_32, N);
    k_agg2<<<(N + 7) / 8, 256, 0, stream>>>(csr, row_start, t2_32, dis, aggv32, N);
    k_gemm2<<<(N + G2_ROWS - 1) / G2_ROWS, 256, 0, stream>>>(aggv32, W2, b2, out, N);
}

// Round 15
// 872.093 us; speedup vs baseline: 1.3237x; 1.3237x over previous
//
#include <hip/hip_runtime.h>
#include <stdint.h>

// x[N,128] f32, edge_index[2,E] int32/64, ew[E] f32, W1[64,128], b1[64], W2[128,64], b2[128]
#define FIN 128
#define FHID 64
#define CHUNK 2048
#define FIX_SCALE 65536.0f      // 2^16 fixed point for weighted degree
#define FIX_INV   (1.0f / 65536.0f)
#define AGG_SC    262144.0f     // 2^18 fixed point for order-invariant aggregation
#define AGG_INV   (1.0f / 262144.0f)

__device__ __forceinline__ float bf2f(unsigned short u) {
    union { unsigned int i; float f; } v; v.i = ((unsigned int)u) << 16; return v.f;
}
__device__ __forceinline__ unsigned short f2bf(float f) {
    union { float f; unsigned int i; } v; v.f = f;
    unsigned int u = v.i;
    u += 0x7FFFu + ((u >> 16) & 1u);   // round-to-nearest-even
    return (unsigned short)(u >> 16);
}

// ---------- dtype detection: int64 edge_index has odd 32-bit words == 0 ----------
__global__ void k_detect(const uint32_t* __restrict__ ei, int* __restrict__ flag) {
    if (blockIdx.x == 0 && threadIdx.x == 0) {
        uint32_t o = 0;
        #pragma unroll
        for (int i = 1; i < 16; i += 2) o |= ei[i];
        *flag = (o == 0) ? 1 : 0;
    }
}

__device__ __forceinline__ int edge_at(const void* ei, long long idx, int is64) {
    if (is64) return (int)((const long long*)ei)[idx];
    return ((const int*)ei)[idx];
}

// ---------- FUSED: gemm1 tile (blocks < g1b) + packed-degree histogram ----------
// r13-proven form: monolithic Wt (2 barriers total). r14 lesson: phased staging
// with 8 barriers under the atomic storm makes gemm blocks stragglers (599 us).
__global__ __launch_bounds__(256) void k_deg_gemm1(const float* __restrict__ x, const float* __restrict__ W1,
                                                   unsigned short* __restrict__ h1lin,
                                                   const void* __restrict__ ei, const float* __restrict__ w,
                                                   unsigned int* __restrict__ packed,
                                                   unsigned char* __restrict__ rank,
                                                   const int* __restrict__ flag, int E, int N, int g1b) {
    if (blockIdx.x < g1b) {
        __shared__ float Wt[FIN * 65];      // Wt[k*65+j] = W1[j*128+k], conflict-free
        __shared__ float xt[32 * FIN];      // 16 KB
        int t = threadIdx.x;
        for (int i = t; i < FHID * FIN; i += 256) {
            int j = i >> 7, k = i & 127;
            Wt[k * 65 + j] = W1[i];
        }
        int r0 = blockIdx.x * 32;
        const float4* xg = (const float4*)(x + (size_t)r0 * FIN);
        float4* xt4 = (float4*)xt;
        #pragma unroll
        for (int q = 0; q < 4; ++q) {
            int i = t + q * 256;
            if (r0 + (i >> 5) < N) xt4[i] = xg[i];
        }
        __syncthreads();
        int j = t & 63, rg = t >> 6;
        float acc[8];
        #pragma unroll
        for (int r = 0; r < 8; ++r) acc[r] = 0.f;
        for (int kk = 0; kk < FIN; kk += 4) {
            float w0 = Wt[(kk + 0) * 65 + j];
            float w1 = Wt[(kk + 1) * 65 + j];
            float w2 = Wt[(kk + 2) * 65 + j];
            float w3 = Wt[(kk + 3) * 65 + j];
            #pragma unroll
            for (int r = 0; r < 8; ++r) {
                float4 xv = xt4[(rg * 8 + r) * 32 + (kk >> 2)];
                acc[r] += xv.x * w0 + xv.y * w1 + xv.z * w2 + xv.w * w3;
            }
        }
        #pragma unroll
        for (int r = 0; r < 8; ++r) {
            int row = r0 + rg * 8 + r;
            if (row < N) h1lin[(size_t)row * FHID + j] = f2bf(acc[r]);
        }
    }
    // ---- edge histogram part (all blocks) ----
    int e = blockIdx.x * 256 + threadIdx.x;
    if (e >= E) return;
    int is64 = *flag;
    int c = edge_at(ei, (long long)E + e, is64);
    unsigned int inc = (1u << 24) | __float2uint_rn(w[e] * FIX_SCALE);
    unsigned int old = atomicAdd(&packed[c], inc);
    rank[e] = (unsigned char)(old >> 24);
}

// ---------- merged: dis = deg^-1/2 AND t1 = dis[row] * h1lin (in place) ----------
// One pass over t1; rsqrt recomputed per word from L1-broadcast packed[node].
__global__ __launch_bounds__(256) void k_dis_scale(const unsigned int* __restrict__ packed,
                                                   float* __restrict__ dis,
                                                   unsigned int* __restrict__ t, int total) {
    int i = blockIdx.x * 256 + threadIdx.x;
    if (i >= total) return;
    int node = i >> 5;                      // 32 consecutive words share one node
    float d = (float)(packed[node] & 0xFFFFFFu) * FIX_INV;
    d = (d > 0.f) ? rsqrtf(d) : 0.f;
    if ((i & 31) == 0) dis[node] = d;
    unsigned v = t[i];
    t[i] = (unsigned)f2bf(bf2f((unsigned short)v) * d)
         | ((unsigned)f2bf(bf2f((unsigned short)(v >> 16)) * d) << 16);
}

// ---------- exclusive scan of packed counts -> row_start ----------
__global__ __launch_bounds__(256) void k_scan_part(const unsigned int* __restrict__ packed,
                                                   int* __restrict__ partial, int N) {
    __shared__ int sdata[256];
    int b = blockIdx.x, t = threadIdx.x;
    int base = b * CHUNK;
    int sum = 0;
    #pragma unroll
    for (int q = 0; q < CHUNK / 256; ++q) {
        int idx = base + q * 256 + t;
        if (idx < N) sum += (int)(packed[idx] >> 24);
    }
    sdata[t] = sum; __syncthreads();
    for (int off = 128; off > 0; off >>= 1) {
        if (t < off) sdata[t] += sdata[t + off];
        __syncthreads();
    }
    if (t == 0) partial[b] = sdata[0];
}

__global__ void k_scan_top(int* partial, int nparts, int* row_start, int N) {
    if (blockIdx.x == 0 && threadIdx.x == 0) {
        int run = 0;
        for (int i = 0; i < nparts; ++i) { int v = partial[i]; partial[i] = run; run += v; }
        row_start[N] = run;   // == E
    }
}

__global__ __launch_bounds__(256) void k_scan_chunk(const unsigned int* __restrict__ packed,
                                                    const int* __restrict__ partial,
                                                    int* __restrict__ row_start, int N) {
    __shared__ int tsum[256];
    __shared__ int toff[256];
    int b = blockIdx.x, t = threadIdx.x;
    int base = b * CHUNK + t * 8;
    int v[8]; int s = 0;
    #pragma unroll
    for (int q = 0; q < 8; ++q) {
        int idx = base + q;
        v[q] = (idx < N) ? (int)(packed[idx] >> 24) : 0;
        s += v[q];
    }
    tsum[t] = s; __syncthreads();
    if (t == 0) {
        int run = partial[b];
        for (int i = 0; i < 256; ++i) { int x = tsum[i]; toff[i] = run; run += x; }
    }
    __syncthreads();
    int ex = toff[t];
    #pragma unroll
    for (int q = 0; q < 8; ++q) {
        int idx = base + q;
        if (idx < N) row_start[idx] = ex;
        ex += v[q];
    }
}

// ---------- CSR fill (atomic-free, no dis gathers): csr = {src, w} ----------
__global__ __launch_bounds__(256) void k_fill(const void* __restrict__ ei, const float* __restrict__ w,
                                              const int* __restrict__ row_start,
                                              const unsigned char* __restrict__ rank,
                                              int2* __restrict__ csr,
                                              const int* __restrict__ flag, int E) {
    int e = blockIdx.x * 256 + threadIdx.x;
    if (e >= E) return;
    int is64 = *flag;
    int r = edge_at(ei, e, is64);
    int c = edge_at(ei, (long long)E + e, is64);
    int pos = row_start[c] + (int)rank[e];
    csr[pos] = make_int2(r, __float_as_int(w[e]));
}

// ---------- dual-node interleaved pair-gather aggregation (int-fx, order-invariant) ----------
// acc = sum w * tab[src]; caller multiplies by dis[node] (factored-out dis[c]).
// OUT_MODE 0 (agg1): t2 = dis*relu(dis*acc + b1);  OUT_MODE 1 (agg2): aggv = dis*acc
template <int OUT_MODE>
__device__ __forceinline__ void agg_fx_dual(const int2* __restrict__ csr, const int* __restrict__ row_start,
                                            const unsigned int* __restrict__ tab32,
                                            const float* __restrict__ b1, const float* __restrict__ dis,
                                            unsigned int* __restrict__ out32, int N) {
    int wid = threadIdx.x >> 6, lane = threadIdx.x & 63;
    int nodeA = blockIdx.x * 8 + wid * 2;
    if (nodeA >= N) return;
    int nodeB = nodeA + 1;
    bool hasB = nodeB < N;
    int half = lane >> 5, lpos = lane & 31;
    int baseA = row_start[nodeA], eA = row_start[nodeA + 1];
    int baseB = hasB ? eA : 0, eB = hasB ? row_start[nodeB + 1] : 0;
    int aAx0 = 0, aAy0 = 0, aAx1 = 0, aAy1 = 0;
    int aBx0 = 0, aBy0 = 0, aBx1 = 0, aBy1 = 0;
    while (baseA < eA || baseB < eB) {
        int mA = eA - baseA; mA = mA < 0 ? 0 : (mA > 64 ? 64 : mA);
        int mB = eB - baseB; mB = mB < 0 ? 0 : (mB > 64 ? 64 : mB);
        int2 entA = (lane < mA) ? csr[baseA + lane] : make_int2(0, 0);
        int2 entB = (lane < mB) ? csr[baseB + lane] : make_int2(0, 0);
        int mMax = mA > mB ? mA : mB;
        int i = 0;
        for (; i + 4 <= mMax; i += 4) {
            if (i < mA) {
                int s0 = __shfl(entA.x, i + half);     float n0 = __shfl(__int_as_float(entA.y), i + half);
                int s1 = __shfl(entA.x, i + 2 + half); float n1 = __shfl(__int_as_float(entA.y), i + 2 + half);
                unsigned v0 = tab32[(size_t)((unsigned)s0 << 5) + lpos];
                unsigned v1 = tab32[(size_t)((unsigned)s1 << 5) + lpos];
                float f0 = n0 * AGG_SC, f1 = n1 * AGG_SC;
                aAx0 += __float2int_rz(f0 * bf2f((unsigned short)v0));
                aAy0 += __float2int_rz(f0 * bf2f((unsigned short)(v0 >> 16)));
                aAx1 += __float2int_rz(f1 * bf2f((unsigned short)v1));
                aAy1 += __float2int_rz(f1 * bf2f((unsigned short)(v1 >> 16)));
            }
            if (i < mB) {
                int s0 = __shfl(entB.x, i + half);     float n0 = __shfl(__int_as_float(entB.y), i + half);
                int s1 = __shfl(entB.x, i + 2 + half); float n1 = __shfl(__int_as_float(entB.y), i + 2 + half);
                unsigned v0 = tab32[(size_t)((unsigned)s0 << 5) + lpos];
                unsigned v1 = tab32[(size_t)((unsigned)s1 << 5) + lpos];
                float f0 = n0 * AGG_SC, f1 = n1 * AGG_SC;
                aBx0 += __float2int_rz(f0 * bf2f((unsigned short)v0));
                aBy0 += __float2int_rz(f0 * bf2f((unsigned short)(v0 >> 16)));
                aBx1 += __float2int_rz(f1 * bf2f((unsigned short)v1));
                aBy1 += __float2int_rz(f1 * bf2f((unsigned short)(v1 >> 16)));
            }
        }
        for (; i < mMax; ++i) {
            if (i < mA) {
                int s0 = __shfl(entA.x, i); float n0 = __shfl(__int_as_float(entA.y), i);
                if (half) n0 = 0.f;
                unsigned v0 = tab32[(size_t)((unsigned)s0 << 5) + lpos];
                float f0 = n0 * AGG_SC;
                aAx0 += __float2int_rz(f0 * bf2f((unsigned short)v0));
                aAy0 += __float2int_rz(f0 * bf2f((unsigned short)(v0 >> 16)));
            }
            if (i < mB) {
                int s0 = __shfl(entB.x, i); float n0 = __shfl(__int_as_float(entB.y), i);
                if (half) n0 = 0.f;
                unsigned v0 = tab32[(size_t)((unsigned)s0 << 5) + lpos];
                float f0 = n0 * AGG_SC;
                aBx0 += __float2int_rz(f0 * bf2f((unsigned short)v0));
                aBy0 += __float2int_rz(f0 * bf2f((unsigned short)(v0 >> 16)));
            }
        }
        baseA += 64; baseB += 64;
    }
    int axA = aAx0 + aAx1, ayA = aAy0 + aAy1;
    axA += __shfl_xor(axA, 32); ayA += __shfl_xor(ayA, 32);   // int: order-invariant
    int axB = aBx0 + aBx1, ayB = aBy0 + aBy1;
    axB += __shfl_xor(axB, 32); ayB += __shfl_xor(ayB, 32);
    if (lane < 32) {
        float dA = dis[nodeA];
        float dB = hasB ? dis[nodeB] : 0.f;
        float fxA = (float)axA * AGG_INV * dA, fyA = (float)ayA * AGG_INV * dA;
        float fxB = (float)axB * AGG_INV * dB, fyB = (float)ayB * AGG_INV * dB;
        if (OUT_MODE == 0) {
            float2 bp = ((const float2*)b1)[lane];
            fxA = dA * fmaxf(fxA + bp.x, 0.f); fyA = dA * fmaxf(fyA + bp.y, 0.f);
            fxB = dB * fmaxf(fxB + bp.x, 0.f); fyB = dB * fmaxf(fyB + bp.y, 0.f);
        }
        out32[(size_t)nodeA * 32 + lane] = (unsigned)f2bf(fxA) | ((unsigned)f2bf(fyA) << 16);
        if (hasB)
            out32[(size_t)nodeB * 32 + lane] = (unsigned)f2bf(fxB) | ((unsigned)f2bf(fyB) << 16);
    }
}

__global__ __launch_bounds__(256) void k_agg1(const int2* __restrict__ csr, const int* __restrict__ row_start,
                                              const unsigned int* __restrict__ t1,
                                              const float* __restrict__ b1, const float* __restrict__ dis,
                                              unsigned int* __restrict__ t2, int N) {
    agg_fx_dual<0>(csr, row_start, t1, b1, dis, t2, N);
}

__global__ __launch_bounds__(256) void k_agg2(const int2* __restrict__ csr, const int* __restrict__ row_start,
                                              const unsigned int* __restrict__ t2,
                                              const float* __restrict__ dis,
                                              unsigned int* __restrict__ aggv32, int N) {
    agg_fx_dual<1>(csr, row_start, t2, (const float*)nullptr, dis, aggv32, N);
}

// ---------- GEMM2: out[N,128] = relu(aggv[N,64](bf16) @ W2[128,64]^T + b2) ----------
#define G2_ROWS 16
__global__ __launch_bounds__(256, 4) void k_gemm2(const unsigned int* __restrict__ aggv32,
                                                  const float* __restrict__ W2,
                                                  const float* __restrict__ b2,
                                                  float* __restrict__ out, int N) {
    __shared__ float Wt[FHID * 129];            // Wt[k*129+j] = W2[j*64+k]; conflict-free
    __shared__ unsigned int at[G2_ROWS * 33];
    int t = threadIdx.x;
    for (int i = t; i < FIN * FHID; i += 256) {
        int j = i >> 6, k = i & 63;
        Wt[k * 129 + j] = W2[i];
    }
    int r0 = blockIdx.x * G2_ROWS;
    for (int i = t; i < G2_ROWS * 32; i += 256) {
        int r = i >> 5, c = i & 31;
        at[r * 33 + c] = (r0 + r < N) ? aggv32[(size_t)(r0 + r) * 32 + c] : 0u;
    }
    __syncthreads();
    int j = t & 127, rg = t >> 7;
    float acc[8];
    #pragma unroll
    for (int r = 0; r < 8; ++r) acc[r] = 0.f;
    for (int c = 0; c < 32; c += 2) {
        float w0 = Wt[(2 * c + 0) * 129 + j];
        float w1 = Wt[(2 * c + 1) * 129 + j];
        float w2 = Wt[(2 * c + 2) * 129 + j];
        float w3 = Wt[(2 * c + 3) * 129 + j];
        #pragma unroll
        for (int r = 0; r < 8; ++r) {
            unsigned a01 = at[(rg * 8 + r) * 33 + c];
            unsigned a23 = at[(rg * 8 + r) * 33 + c + 1];
            acc[r] += bf2f((unsigned short)a01) * w0 + bf2f((unsigned short)(a01 >> 16)) * w1
                    + bf2f((unsigned short)a23) * w2 + bf2f((unsigned short)(a23 >> 16)) * w3;
        }
    }
    float bj = b2[j];
    #pragma unroll
    for (int r = 0; r < 8; ++r) {
        int row = r0 + rg * 8 + r;
        if (row < N) out[(size_t)row * FIN + j] = fmaxf(acc[r] + bj, 0.f);
    }
}

extern "C" void kernel_launch(void* const* d_in, const int* in_sizes, int n_in,
                              void* d_out, int out_size, void* d_ws, size_t ws_size,
                              hipStream_t stream) {
    const float* x  = (const float*)d_in[0];
    const void*  ei = d_in[1];
    const float* w  = (const float*)d_in[2];
    const float* W1 = (const float*)d_in[3];
    const float* b1 = (const float*)d_in[4];
    const float* W2 = (const float*)d_in[5];
    const float* b2 = (const float*)d_in[6];
    float* out = (float*)d_out;
    int N = in_sizes[0] / FIN;
    int E = in_sizes[2];

    char* ws = (char*)d_ws;
    size_t off = 0;
    auto alloc = [&](size_t b) { size_t o = off; off = (off + b + 255) & ~255ULL; return o; };
    int*   flag      = (int*)(ws + alloc(4));
    unsigned int* packed = (unsigned int*)(ws + alloc((size_t)N * 4));
    float* dis       = (float*)(ws + alloc((size_t)N * 4));
    int*   row_start = (int*)(ws + alloc((size_t)(N + 1) * 4));
    int*   partial   = (int*)(ws + alloc(4096));
    int2*  csr       = (int2*)(ws + alloc((size_t)E * 8));
    unsigned char* rank = (unsigned char*)(ws + alloc((size_t)E));   // own slot (fused kernel writes h1lin too)
    unsigned int* t2_32   = (unsigned int*)(ws + alloc((size_t)N * FHID * 2));
    unsigned int* aggv32  = (unsigned int*)(ws + alloc((size_t)N * FHID * 2));
    unsigned int* t1_32   = (unsigned int*)(ws + alloc((size_t)N * FHID * 2));  // h1lin then t1 (scaled in place)

    hipMemsetAsync(packed, 0, (size_t)N * 4, stream);

    k_detect<<<1, 64, 0, stream>>>((const uint32_t*)ei, flag);

    int eb = (E + 255) / 256;
    int g1b = (N + 31) / 32;
    int fused_grid = eb > g1b ? eb : g1b;
    k_deg_gemm1<<<fused_grid, 256, 0, stream>>>(x, W1, (unsigned short*)t1_32, ei, w,
                                                packed, rank, flag, E, N, g1b);
    k_dis_scale<<<(N * 32 + 255) / 256, 256, 0, stream>>>(packed, dis, t1_32, N * 32);

    int nparts = (N + CHUNK - 1) / CHUNK;
    k_scan_part<<<nparts, 256, 0, stream>>>(packed, partial, N);
    k_scan_top<<<1, 64, 0, stream>>>(partial, nparts, row_start, N);
    k_scan_chunk<<<nparts, 256, 0, stream>>>(packed, partial, row_start, N);

    k_fill<<<eb, 256, 0, stream>>>(ei, w, row_start, rank, csr, flag, E);

    k_agg1<<<(N + 7) / 8, 256, 0, stream>>>(csr, row_start, t1_32, b1, dis, t2_32, N);
    k_agg2<<<(N + 7) / 8, 256, 0, stream>>>(csr, row_start, t2_32, dis, aggv32, N);
    k_gemm2<<<(N + G2_ROWS - 1) / G2_ROWS, 256, 0, stream>>>(aggv32, W2, b2, out, N);
}